// Round 1
// baseline (357.746 us; speedup 1.0000x reference)
//
#include <hip/hip_runtime.h>
#include <cstddef>
#include <cstdint>

// Problem constants (KPNextBlock): M=N=50000, H=32, C=128, K=15, GROUPS=8,
// CPG=16 -> K*CPG=240, RADIUS=1.2, SIGMA=0.9.
namespace {
constexpr int H_N  = 32;
constexpr int C_F  = 128;
constexpr int K_P  = 15;
constexpr int MODC = 240;   // K * CPG
}

// ---------------------------------------------------------------------------
// Kernel A: modulations = sigmoid(leaky_relu(s_feats @ w1 + b1, 0.1) @ w2)
// One block = 64 rows, 256 threads. LDS: x tile (32KB) + h tile (32KB).
// mod is chunk-local: row r of mod corresponds to query (m_base + r0 + r).
// ---------------------------------------------------------------------------
__global__ __launch_bounds__(256)
void mod_kernel(const float* __restrict__ s_feats,
                const float* __restrict__ w1,
                const float* __restrict__ b1,
                const float* __restrict__ w2,
                float* __restrict__ mod,
                int m_base, int rows_total)
{
    __shared__ float xs[64][C_F];
    __shared__ float hs[64][C_F];
    const int r0 = blockIdx.x * 64;
    int rows = rows_total - r0; if (rows > 64) rows = 64;
    const int t = threadIdx.x;

    // load x tile (float4, coalesced)
    for (int i = t; i < rows * 32; i += 256) {
        const int r = i >> 5, c4 = i & 31;
        reinterpret_cast<float4*>(&xs[r][0])[c4] =
            reinterpret_cast<const float4*>(s_feats + (size_t)(m_base + r0 + r) * C_F)[c4];
    }
    __syncthreads();

    // h = leaky_relu(x @ w1 + b1)
    for (int i = t; i < rows * 32; i += 256) {
        const int r = i >> 5, j4 = i & 31, j = j4 << 2;
        float4 a = *reinterpret_cast<const float4*>(b1 + j);
        #pragma unroll 4
        for (int c = 0; c < C_F; ++c) {
            const float x = xs[r][c];
            const float4 w = *reinterpret_cast<const float4*>(w1 + c * C_F + j);
            a.x = fmaf(x, w.x, a.x); a.y = fmaf(x, w.y, a.y);
            a.z = fmaf(x, w.z, a.z); a.w = fmaf(x, w.w, a.w);
        }
        a.x = a.x > 0.f ? a.x : 0.1f * a.x;
        a.y = a.y > 0.f ? a.y : 0.1f * a.y;
        a.z = a.z > 0.f ? a.z : 0.1f * a.z;
        a.w = a.w > 0.f ? a.w : 0.1f * a.w;
        reinterpret_cast<float4*>(&hs[r][0])[j4] = a;
    }
    __syncthreads();

    // mod = sigmoid(h @ w2)   (240 cols = 60 float4)
    for (int i = t; i < rows * 60; i += 256) {
        const int r = i / 60, j4 = i - r * 60, j = j4 << 2;
        float4 a = {0.f, 0.f, 0.f, 0.f};
        #pragma unroll 4
        for (int c = 0; c < C_F; ++c) {
            const float x = hs[r][c];
            const float4 w = *reinterpret_cast<const float4*>(w2 + c * MODC + j);
            a.x = fmaf(x, w.x, a.x); a.y = fmaf(x, w.y, a.y);
            a.z = fmaf(x, w.z, a.z); a.w = fmaf(x, w.w, a.w);
        }
        float4 o;
        o.x = 1.f / (1.f + __expf(-a.x));
        o.y = 1.f / (1.f + __expf(-a.y));
        o.z = 1.f / (1.f + __expf(-a.z));
        o.w = 1.f / (1.f + __expf(-a.w));
        *reinterpret_cast<float4*>(mod + (size_t)(r0 + r) * MODC + j) = o;
    }
}

// ---------------------------------------------------------------------------
// Kernel B: geometry + sparse gather/accumulate. One wave (64 lanes) per query.
// Lanes 0..31 each handle one neighbor's geometry; all 64 lanes accumulate
// 2 channels each. Wave-uniform skip of zero-influence neighbors via ballot.
// ---------------------------------------------------------------------------
__global__ __launch_bounds__(256)
void kpconv_kernel(const float* __restrict__ q_pts,
                   const float* __restrict__ s_pts,
                   const float* __restrict__ s_feats,
                   const int* __restrict__ nbi,
                   const float* __restrict__ da_scale,
                   const float* __restrict__ weights,
                   const float* __restrict__ kp,
                   const float* __restrict__ mod,   // chunk-local [rows, 240]
                   float* __restrict__ out,
                   int m_base, int rows_total)
{
    const int t    = threadIdx.x;
    const int lane = t & 63;
    const int r    = blockIdx.x * 4 + (t >> 6);
    if (r >= rows_total) return;
    const int m = m_base + r;

    const float qx = q_pts[m * 3 + 0];
    const float qy = q_pts[m * 3 + 1];
    const float qz = q_pts[m * 3 + 2];
    const float das = da_scale[m];

    int   idx = 0, nn = 0;
    float fl  = 0.f;
    if (lane < H_N) {
        idx = nbi[(size_t)m * H_N + lane];
        const float sx = s_pts[idx * 3 + 0];
        const float sy = s_pts[idx * 3 + 1];
        const float sz = s_pts[idx * 3 + 2];
        // plain fp32 (no fma contraction) to match numpy rounding at argmin ties
        const float dx = __fsub_rn(sx, qx);
        const float dy = __fsub_rn(sy, qy);
        const float dz = __fsub_rn(sz, qz);
        const float dd = __fadd_rn(__fadd_rn(__fmul_rn(dx, dx), __fmul_rn(dy, dy)),
                                   __fmul_rn(dz, dz));
        // bounding-sphere reject: |kp| < RADIUS=1.2 strictly, so if
        // |d| >= 0.9 + 1.2*da then nearest-kp dist > 0.9 => infl == 0 exactly.
        const float reach = 0.9f + 1.2f * das;
        if (dd < reach * reach) {
            float best = 3.4e38f; int bi = 0;
            #pragma unroll
            for (int k = 0; k < K_P; ++k) {
                const float ex = __fsub_rn(dx, __fmul_rn(kp[k * 3 + 0], das));
                const float ey = __fsub_rn(dy, __fmul_rn(kp[k * 3 + 1], das));
                const float ez = __fsub_rn(dz, __fmul_rn(kp[k * 3 + 2], das));
                const float d2 = __fadd_rn(__fadd_rn(__fmul_rn(ex, ex), __fmul_rn(ey, ey)),
                                           __fmul_rn(ez, ez));
                if (d2 < best) { best = d2; bi = k; }
            }
            const float f = 1.f - sqrtf(best) / 0.9f;
            fl = fmaxf(f, 0.f);
            nn = bi;
        }
    }

    unsigned long long mask = __ballot(fl > 0.f);
    const int c0 = lane << 1;
    float2 acc = {0.f, 0.f};
    while (mask) {
        const int h = __builtin_ctzll(mask);
        mask &= mask - 1;
        const int   ih = __shfl(idx, h);
        const int   nh = __shfl(nn, h);
        const float fh = __shfl(fl, h);
        const float2 fv = *reinterpret_cast<const float2*>(s_feats + (size_t)ih * C_F + c0);
        const float2 wv = *reinterpret_cast<const float2*>(weights + nh * C_F + c0);
        const float  mv = mod[(size_t)r * MODC + nh * 16 + (lane >> 2)];
        const float  s  = fh * mv;
        acc.x = fmaf(fv.x * wv.x, s, acc.x);
        acc.y = fmaf(fv.y * wv.y, s, acc.y);
    }
    reinterpret_cast<float2*>(out + (size_t)m * C_F)[lane] = acc;
}

// ---------------------------------------------------------------------------
extern "C" void kernel_launch(void* const* d_in, const int* in_sizes, int n_in,
                              void* d_out, int out_size, void* d_ws, size_t ws_size,
                              hipStream_t stream)
{
    const float* q_pts  = (const float*)d_in[0];
    const float* s_pts  = (const float*)d_in[1];
    const float* s_feat = (const float*)d_in[2];
    const int*   nbi    = (const int*)d_in[3];
    const float* da     = (const float*)d_in[4];
    const float* wts    = (const float*)d_in[5];
    const float* w1     = (const float*)d_in[6];
    const float* b1     = (const float*)d_in[7];
    const float* w2     = (const float*)d_in[8];
    const float* kp     = (const float*)d_in[9];
    float* out = (float*)d_out;
    float* mod = (float*)d_ws;

    const int M = in_sizes[4];   // da_scale has M elements

    // mod needs M*240*4 = 48 MB; chunk if the workspace is smaller.
    size_t cap = ws_size / ((size_t)MODC * sizeof(float));
    int chunk = (cap >= (size_t)M) ? M : (int)(cap & ~(size_t)3);
    if (chunk < 4) chunk = 4;

    for (int m0 = 0; m0 < M; m0 += chunk) {
        int rows = M - m0; if (rows > chunk) rows = chunk;
        mod_kernel<<<dim3((rows + 63) / 64), 256, 0, stream>>>(
            s_feat, w1, b1, w2, mod, m0, rows);
        kpconv_kernel<<<dim3((rows + 3) / 4), 256, 0, stream>>>(
            q_pts, s_pts, s_feat, nbi, da, wts, kp, mod, out, m0, rows);
    }
}

// Round 2
// 101.889 us; speedup vs baseline: 3.5111x; 3.5111x over previous
//
#include <hip/hip_runtime.h>
#include <cstddef>
#include <cstdint>

// Problem constants (KPNextBlock): M=N=50000, H=32, C=128, K=15, GROUPS=8,
// CPG=16 -> K*CPG=240, RADIUS=1.2, SIGMA=0.9.
namespace {
constexpr int H_N  = 32;
constexpr int C_F  = 128;
constexpr int K_P  = 15;
constexpr int MODC = 240;   // K * CPG
}

__device__ __forceinline__ void fma4(float4& a, float s, const float4& w) {
    a.x = fmaf(s, w.x, a.x);
    a.y = fmaf(s, w.y, a.y);
    a.z = fmaf(s, w.z, a.z);
    a.w = fmaf(s, w.w, a.w);
}

// ---------------------------------------------------------------------------
// Kernel A: modulations = sigmoid(leaky_relu(s_feats @ w1 + b1, 0.1) @ w2)
// Block = 64 rows x 256 threads, register-blocked over rows so each weight
// float4 load feeds 8 (phase1) / 16 (phase2) rows worth of FMAs.
// One 32KB LDS buffer reused for x then h.
// ---------------------------------------------------------------------------
__global__ __launch_bounds__(256)
void mod_kernel(const float* __restrict__ s_feats,
                const float* __restrict__ w1,
                const float* __restrict__ b1,
                const float* __restrict__ w2,
                float* __restrict__ mod,
                int m_base, int rows_total)
{
    __shared__ float xs[64][C_F];
    const int r0 = blockIdx.x * 64;
    int rows = rows_total - r0; if (rows > 64) rows = 64;
    const int t = threadIdx.x;

    // stage x tile (float4, coalesced)
    for (int i = t; i < rows * 32; i += 256) {
        const int r = i >> 5, c4 = i & 31;
        reinterpret_cast<float4*>(&xs[r][0])[c4] =
            reinterpret_cast<const float4*>(s_feats + (size_t)(m_base + r0 + r) * C_F)[c4];
    }
    __syncthreads();

    // ---- phase 1: h = leaky_relu(x @ w1 + b1) ----
    // thread (rga, j4a): rows rga*8..+7, output cols j4a*4..+3
    const int j4a = t & 31;
    const int rga = t >> 5;
    float4 hacc[8];
    {
        const float4 bv = *reinterpret_cast<const float4*>(b1 + j4a * 4);
        #pragma unroll
        for (int rr = 0; rr < 8; ++rr) hacc[rr] = bv;
        const float4* wp = reinterpret_cast<const float4*>(w1) + j4a;  // row stride 32
        for (int c = 0; c < C_F; c += 4) {
            const float4 wa = wp[(c + 0) * 32];
            const float4 wb = wp[(c + 1) * 32];
            const float4 wc = wp[(c + 2) * 32];
            const float4 wd = wp[(c + 3) * 32];
            #pragma unroll
            for (int rr = 0; rr < 8; ++rr) {
                const float4 xv = *reinterpret_cast<const float4*>(&xs[rga * 8 + rr][c]);
                fma4(hacc[rr], xv.x, wa);
                fma4(hacc[rr], xv.y, wb);
                fma4(hacc[rr], xv.z, wc);
                fma4(hacc[rr], xv.w, wd);
            }
        }
    }
    __syncthreads();   // everyone done READING xs
    #pragma unroll
    for (int rr = 0; rr < 8; ++rr) {
        float4 a = hacc[rr];
        a.x = a.x > 0.f ? a.x : 0.1f * a.x;
        a.y = a.y > 0.f ? a.y : 0.1f * a.y;
        a.z = a.z > 0.f ? a.z : 0.1f * a.z;
        a.w = a.w > 0.f ? a.w : 0.1f * a.w;
        *reinterpret_cast<float4*>(&xs[rga * 8 + rr][j4a * 4]) = a;   // h into xs
    }
    __syncthreads();

    // ---- phase 2: mod = sigmoid(h @ w2) ----
    // thread (rg, j4): rows rg*16..+15, output cols j4*4..+3 (240 threads)
    if (t < 240) {
        const int j4 = t % 60;
        const int rg = t / 60;
        float4 acc[16];
        #pragma unroll
        for (int rr = 0; rr < 16; ++rr) acc[rr] = make_float4(0.f, 0.f, 0.f, 0.f);
        const float4* wp = reinterpret_cast<const float4*>(w2) + j4;   // row stride 60
        for (int c = 0; c < C_F; c += 4) {
            const float4 wa = wp[(c + 0) * 60];
            const float4 wb = wp[(c + 1) * 60];
            const float4 wc = wp[(c + 2) * 60];
            const float4 wd = wp[(c + 3) * 60];
            #pragma unroll
            for (int rr = 0; rr < 16; ++rr) {
                const float4 xv = *reinterpret_cast<const float4*>(&xs[rg * 16 + rr][c]);
                fma4(acc[rr], xv.x, wa);
                fma4(acc[rr], xv.y, wb);
                fma4(acc[rr], xv.z, wc);
                fma4(acc[rr], xv.w, wd);
            }
        }
        #pragma unroll
        for (int rr = 0; rr < 16; ++rr) {
            const int r = rg * 16 + rr;
            if (r < rows) {
                float4 o;
                o.x = 1.f / (1.f + __expf(-acc[rr].x));
                o.y = 1.f / (1.f + __expf(-acc[rr].y));
                o.z = 1.f / (1.f + __expf(-acc[rr].z));
                o.w = 1.f / (1.f + __expf(-acc[rr].w));
                *reinterpret_cast<float4*>(mod + (size_t)(r0 + r) * MODC + j4 * 4) = o;
            }
        }
    }
}

// ---------------------------------------------------------------------------
// Kernel B: geometry + sparse gather/accumulate. One wave (64 lanes) per query.
// ---------------------------------------------------------------------------
__global__ __launch_bounds__(256)
void kpconv_kernel(const float* __restrict__ q_pts,
                   const float* __restrict__ s_pts,
                   const float* __restrict__ s_feats,
                   const int* __restrict__ nbi,
                   const float* __restrict__ da_scale,
                   const float* __restrict__ weights,
                   const float* __restrict__ kp,
                   const float* __restrict__ mod,   // chunk-local [rows, 240]
                   float* __restrict__ out,
                   int m_base, int rows_total)
{
    const int t    = threadIdx.x;
    const int lane = t & 63;
    const int r    = blockIdx.x * 4 + (t >> 6);
    if (r >= rows_total) return;
    const int m = m_base + r;

    const float qx = q_pts[m * 3 + 0];
    const float qy = q_pts[m * 3 + 1];
    const float qz = q_pts[m * 3 + 2];
    const float das = da_scale[m];

    int   idx = 0, nn = 0;
    float fl  = 0.f;
    if (lane < H_N) {
        idx = nbi[(size_t)m * H_N + lane];
        const float sx = s_pts[idx * 3 + 0];
        const float sy = s_pts[idx * 3 + 1];
        const float sz = s_pts[idx * 3 + 2];
        // plain fp32 (no fma contraction) to match numpy rounding at argmin ties
        const float dx = __fsub_rn(sx, qx);
        const float dy = __fsub_rn(sy, qy);
        const float dz = __fsub_rn(sz, qz);
        const float dd = __fadd_rn(__fadd_rn(__fmul_rn(dx, dx), __fmul_rn(dy, dy)),
                                   __fmul_rn(dz, dz));
        // bounding-sphere reject: |kp| < RADIUS=1.2 strictly, so if
        // |d| >= 0.9 + 1.2*da then nearest-kp dist > 0.9 => infl == 0 exactly.
        const float reach = 0.9f + 1.2f * das;
        if (dd < reach * reach) {
            float best = 3.4e38f; int bi = 0;
            #pragma unroll
            for (int k = 0; k < K_P; ++k) {
                const float ex = __fsub_rn(dx, __fmul_rn(kp[k * 3 + 0], das));
                const float ey = __fsub_rn(dy, __fmul_rn(kp[k * 3 + 1], das));
                const float ez = __fsub_rn(dz, __fmul_rn(kp[k * 3 + 2], das));
                const float d2 = __fadd_rn(__fadd_rn(__fmul_rn(ex, ex), __fmul_rn(ey, ey)),
                                           __fmul_rn(ez, ez));
                if (d2 < best) { best = d2; bi = k; }
            }
            const float f = 1.f - sqrtf(best) / 0.9f;
            fl = fmaxf(f, 0.f);
            nn = bi;
        }
    }

    unsigned long long mask = __ballot(fl > 0.f);
    const int c0 = lane << 1;
    float2 acc = {0.f, 0.f};
    while (mask) {
        const int h = __builtin_ctzll(mask);
        mask &= mask - 1;
        const int   ih = __shfl(idx, h);
        const int   nh = __shfl(nn, h);
        const float fh = __shfl(fl, h);
        const float2 fv = *reinterpret_cast<const float2*>(s_feats + (size_t)ih * C_F + c0);
        const float2 wv = *reinterpret_cast<const float2*>(weights + nh * C_F + c0);
        const float  mv = mod[(size_t)r * MODC + nh * 16 + (lane >> 2)];
        const float  s  = fh * mv;
        acc.x = fmaf(fv.x * wv.x, s, acc.x);
        acc.y = fmaf(fv.y * wv.y, s, acc.y);
    }
    reinterpret_cast<float2*>(out + (size_t)m * C_F)[lane] = acc;
}

// ---------------------------------------------------------------------------
extern "C" void kernel_launch(void* const* d_in, const int* in_sizes, int n_in,
                              void* d_out, int out_size, void* d_ws, size_t ws_size,
                              hipStream_t stream)
{
    const float* q_pts  = (const float*)d_in[0];
    const float* s_pts  = (const float*)d_in[1];
    const float* s_feat = (const float*)d_in[2];
    const int*   nbi    = (const int*)d_in[3];
    const float* da     = (const float*)d_in[4];
    const float* wts    = (const float*)d_in[5];
    const float* w1     = (const float*)d_in[6];
    const float* b1     = (const float*)d_in[7];
    const float* w2     = (const float*)d_in[8];
    const float* kp     = (const float*)d_in[9];
    float* out = (float*)d_out;
    float* mod = (float*)d_ws;

    const int M = in_sizes[4];   // da_scale has M elements

    // mod needs M*240*4 = 48 MB; chunk if the workspace is smaller.
    size_t cap = ws_size / ((size_t)MODC * sizeof(float));
    int chunk = (cap >= (size_t)M) ? M : (int)(cap & ~(size_t)3);
    if (chunk < 4) chunk = 4;

    for (int m0 = 0; m0 < M; m0 += chunk) {
        int rows = M - m0; if (rows > chunk) rows = chunk;
        mod_kernel<<<dim3((rows + 63) / 64), 256, 0, stream>>>(
            s_feat, w1, b1, w2, mod, m0, rows);
        kpconv_kernel<<<dim3((rows + 3) / 4), 256, 0, stream>>>(
            q_pts, s_pts, s_feat, nbi, da, wts, kp, mod, out, m0, rows);
    }
}

// Round 3
// 67.942 us; speedup vs baseline: 5.2654x; 1.4996x over previous
//
#include <hip/hip_runtime.h>
#include <cstddef>
#include <cstdint>

// KPNextBlock: M=N=50000, H=32, C=128, K=15, GROUPS=8, CPG=16 -> K*CPG=240,
// RADIUS=1.2, SIGMA=0.9.
namespace {
constexpr int H_N    = 32;
constexpr int C_F    = 128;
constexpr int K_P    = 15;
constexpr int MODC   = 240;
constexpr int ROWS_B = 128;   // rows per block
}

typedef __attribute__((ext_vector_type(8))) short short8v;
typedef __attribute__((ext_vector_type(4))) float f32x4;

__device__ __forceinline__ unsigned short bf16_hi(float f) {
    unsigned u = __builtin_bit_cast(unsigned, f);
    unsigned r = (u + 0x7FFFu + ((u >> 16) & 1u)) >> 16;
    return (unsigned short)r;
}
__device__ __forceinline__ float bf16_f(unsigned short h) {
    unsigned u = ((unsigned)h) << 16;
    return __builtin_bit_cast(float, u);
}

__device__ __forceinline__ f32x4 mfma3(short8v ah, short8v al, short8v bh, short8v bl, f32x4 c) {
    // (ah+al)*(bh+bl) dropping al*bl: error ~2^-18 relative -> fp32-class.
    c = __builtin_amdgcn_mfma_f32_16x16x32_bf16(ah, bl, c, 0, 0, 0);
    c = __builtin_amdgcn_mfma_f32_16x16x32_bf16(al, bh, c, 0, 0, 0);
    c = __builtin_amdgcn_mfma_f32_16x16x32_bf16(ah, bh, c, 0, 0, 0);
    return c;
}

// ---------------------------------------------------------------------------
// Pre-pass: split w1 [128][128] and w2 [128][240] into bf16 hi/lo, TRANSPOSED
// to [col][k] so MFMA B-fragments are 16B-contiguous per lane.
// ---------------------------------------------------------------------------
__global__ __launch_bounds__(256)
void split_w_kernel(const float* __restrict__ w1, const float* __restrict__ w2,
                    unsigned short* __restrict__ w1t_hi, unsigned short* __restrict__ w1t_lo,
                    unsigned short* __restrict__ w2t_hi, unsigned short* __restrict__ w2t_lo)
{
    const int i = blockIdx.x * 256 + threadIdx.x;
    if (i < C_F * C_F) {
        const int c = i >> 7, j = i & 127;          // w1[c][j]
        const float v = w1[i];
        const unsigned short h = bf16_hi(v);
        w1t_hi[j * C_F + c] = h;
        w1t_lo[j * C_F + c] = bf16_hi(v - bf16_f(h));
    }
    const int i2 = i - C_F * C_F;
    if (i2 >= 0 && i2 < C_F * MODC) {
        const int c = i2 / MODC, j = i2 - c * MODC; // w2[c][j]
        const float v = w2[i2];
        const unsigned short h = bf16_hi(v);
        w2t_hi[j * C_F + c] = h;
        w2t_lo[j * C_F + c] = bf16_hi(v - bf16_f(h));
    }
}

// ---------------------------------------------------------------------------
// Fused kernel: per block of 128 queries:
//   stage x (bf16 hi/lo, XOR-swizzled LDS) -> MFMA phase1 (h) -> writeback ->
//   MFMA phase2 (mod, sigmoid, in regs) -> two halves: {mod->LDS, kpconv}.
// 8 waves = 2 row-groups (wr) x 4 col-groups (wc); wave owns 4 row-tiles.
// ---------------------------------------------------------------------------
__global__ __launch_bounds__(512, 4)
void fused_kernel(const float* __restrict__ q_pts,
                  const float* __restrict__ s_pts,
                  const float* __restrict__ s_feats,
                  const int* __restrict__ nbi,
                  const float* __restrict__ da_scale,
                  const float* __restrict__ weights,
                  const float* __restrict__ kp,
                  const unsigned short* __restrict__ w1t_hi,
                  const unsigned short* __restrict__ w1t_lo,
                  const unsigned short* __restrict__ w2t_hi,
                  const unsigned short* __restrict__ w2t_lo,
                  const float* __restrict__ b1,
                  float* __restrict__ out,
                  int M)
{
    __shared__ __align__(16) unsigned char lds_raw[65536];   // xhi 32KB | xlo 32KB; later mod 60KB
    float* modl = reinterpret_cast<float*>(lds_raw);

    const int t  = threadIdx.x;
    const int m0 = blockIdx.x * ROWS_B;
    int rows = M - m0; if (rows > ROWS_B) rows = ROWS_B;

    // ---- stage x: fp32 -> bf16 hi/lo, swizzled LDS [row][k] ----
    {
        const int row = t >> 2;
        const int k0  = (t & 3) << 5;
        float xv[32];
        if (row < rows) {
            const float4* src = reinterpret_cast<const float4*>(s_feats + (size_t)(m0 + row) * C_F + k0);
            #pragma unroll
            for (int q = 0; q < 8; ++q) {
                const float4 v = src[q];
                xv[q * 4 + 0] = v.x; xv[q * 4 + 1] = v.y;
                xv[q * 4 + 2] = v.z; xv[q * 4 + 3] = v.w;
            }
        } else {
            #pragma unroll
            for (int q = 0; q < 32; ++q) xv[q] = 0.f;
        }
        #pragma unroll
        for (int s = 0; s < 4; ++s) {
            short8v hv, lv;
            #pragma unroll
            for (int e = 0; e < 8; ++e) {
                const float v = xv[s * 8 + e];
                const unsigned short h = bf16_hi(v);
                hv[e] = (short)h;
                lv[e] = (short)bf16_hi(v - bf16_f(h));
            }
            const unsigned addr = (unsigned)((row * 256 + (k0 + s * 8) * 2) ^ ((row & 7) << 4));
            *reinterpret_cast<short8v*>(lds_raw + addr)         = hv;
            *reinterpret_cast<short8v*>(lds_raw + 32768 + addr) = lv;
        }
    }
    __syncthreads();

    const int wave = t >> 6, lane = t & 63;
    const int wr = wave >> 2;      // row half: rows 64*wr .. +63
    const int wc = wave & 3;       // col group
    const int g  = lane >> 4;      // k-block
    const int ln = lane & 15;

    // ---- phase 1: h = leaky_relu(x @ w1 + b1) ----
    f32x4 acc1[4][2];
    #pragma unroll
    for (int cti = 0; cti < 2; ++cti) {
        const float b = b1[(wc + 4 * cti) * 16 + ln];
        #pragma unroll
        for (int rt = 0; rt < 4; ++rt) acc1[rt][cti] = f32x4{b, b, b, b};
    }
    #pragma unroll
    for (int ks = 0; ks < 4; ++ks) {
        short8v ah[4], al[4];
        #pragma unroll
        for (int rt = 0; rt < 4; ++rt) {
            const int row = wr * 64 + rt * 16 + ln;
            const unsigned addr = (unsigned)((row * 256 + (ks * 32 + g * 8) * 2) ^ ((row & 7) << 4));
            ah[rt] = *reinterpret_cast<const short8v*>(lds_raw + addr);
            al[rt] = *reinterpret_cast<const short8v*>(lds_raw + 32768 + addr);
        }
        #pragma unroll
        for (int cti = 0; cti < 2; ++cti) {
            const int col = (wc + 4 * cti) * 16 + ln;
            const size_t off = (size_t)col * C_F + ks * 32 + g * 8;
            const short8v bh = *reinterpret_cast<const short8v*>(w1t_hi + off);
            const short8v bl = *reinterpret_cast<const short8v*>(w1t_lo + off);
            #pragma unroll
            for (int rt = 0; rt < 4; ++rt)
                acc1[rt][cti] = mfma3(ah[rt], al[rt], bh, bl, acc1[rt][cti]);
        }
    }
    __syncthreads();   // all waves done reading x before h overwrites it

    // ---- leaky_relu + bf16 split + writeback (C/D: col=ln, row=g*4+r) ----
    #pragma unroll
    for (int rt = 0; rt < 4; ++rt) {
        #pragma unroll
        for (int cti = 0; cti < 2; ++cti) {
            const int col = (wc + 4 * cti) * 16 + ln;
            #pragma unroll
            for (int r = 0; r < 4; ++r) {
                float v = acc1[rt][cti][r];
                v = v > 0.f ? v : 0.1f * v;
                const int row = wr * 64 + rt * 16 + g * 4 + r;
                const unsigned short h = bf16_hi(v);
                const unsigned addr = (unsigned)((row * 256 + col * 2) ^ ((row & 7) << 4));
                *reinterpret_cast<unsigned short*>(lds_raw + addr)         = h;
                *reinterpret_cast<unsigned short*>(lds_raw + 32768 + addr) = bf16_hi(v - bf16_f(h));
            }
        }
    }
    __syncthreads();

    // ---- phase 2: mod = sigmoid(h @ w2) (kept in registers) ----
    f32x4 acc2[4][4];
    #pragma unroll
    for (int rt = 0; rt < 4; ++rt)
        #pragma unroll
        for (int cs = 0; cs < 4; ++cs) acc2[rt][cs] = f32x4{0.f, 0.f, 0.f, 0.f};

    #pragma unroll
    for (int ks = 0; ks < 4; ++ks) {
        short8v ah[4], al[4];
        #pragma unroll
        for (int rt = 0; rt < 4; ++rt) {
            const int row = wr * 64 + rt * 16 + ln;
            const unsigned addr = (unsigned)((row * 256 + (ks * 32 + g * 8) * 2) ^ ((row & 7) << 4));
            ah[rt] = *reinterpret_cast<const short8v*>(lds_raw + addr);
            al[rt] = *reinterpret_cast<const short8v*>(lds_raw + 32768 + addr);
        }
        #pragma unroll
        for (int cs = 0; cs < 4; ++cs) {
            const int ctile = wc + 4 * cs;          // wave-uniform guard, static acc idx
            if (ctile < K_P) {
                const int col = ctile * 16 + ln;
                const size_t off = (size_t)col * C_F + ks * 32 + g * 8;
                const short8v bh = *reinterpret_cast<const short8v*>(w2t_hi + off);
                const short8v bl = *reinterpret_cast<const short8v*>(w2t_lo + off);
                #pragma unroll
                for (int rt = 0; rt < 4; ++rt)
                    acc2[rt][cs] = mfma3(ah[rt], al[rt], bh, bl, acc2[rt][cs]);
            }
        }
    }
    // sigmoid in-place
    #pragma unroll
    for (int rt = 0; rt < 4; ++rt)
        #pragma unroll
        for (int cs = 0; cs < 4; ++cs)
            #pragma unroll
            for (int r = 0; r < 4; ++r)
                acc2[rt][cs][r] = 1.f / (1.f + __expf(-acc2[rt][cs][r]));

    // ---- two halves: write mod (64 rows, fp32) into LDS, then kpconv ----
    for (int half = 0; half < 2; ++half) {
        __syncthreads();   // h/x reads done (half 0) / previous kpconv done (half 1)
        if (wr == half) {
            #pragma unroll
            for (int rt = 0; rt < 4; ++rt) {
                #pragma unroll
                for (int cs = 0; cs < 4; ++cs) {
                    const int ctile = wc + 4 * cs;
                    if (ctile < K_P) {
                        const int col = ctile * 16 + ln;
                        #pragma unroll
                        for (int r = 0; r < 4; ++r) {
                            const int row = rt * 16 + g * 4 + r;   // half-local 0..63
                            modl[row * MODC + col] = acc2[rt][cs][r];
                        }
                    }
                }
            }
        }
        __syncthreads();

        for (int i = 0; i < 8; ++i) {
            const int ql = i * 8 + wave;           // 0..63
            if (half * 64 + ql >= rows) continue;
            const int mq = m0 + half * 64 + ql;

            const float qx = q_pts[mq * 3 + 0];
            const float qy = q_pts[mq * 3 + 1];
            const float qz = q_pts[mq * 3 + 2];
            const float das = da_scale[mq];

            int   idx = 0, nn = 0;
            float fl  = 0.f;
            if (lane < H_N) {
                idx = nbi[(size_t)mq * H_N + lane];
                const float sx = s_pts[idx * 3 + 0];
                const float sy = s_pts[idx * 3 + 1];
                const float sz = s_pts[idx * 3 + 2];
                const float dx = __fsub_rn(sx, qx);
                const float dy = __fsub_rn(sy, qy);
                const float dz = __fsub_rn(sz, qz);
                const float dd = __fadd_rn(__fadd_rn(__fmul_rn(dx, dx), __fmul_rn(dy, dy)),
                                           __fmul_rn(dz, dz));
                // |kp| < 1.2 strictly => |d| >= 0.9 + 1.2*da implies infl == 0 exactly.
                const float reach = 0.9f + 1.2f * das;
                if (dd < reach * reach) {
                    float best = 3.4e38f; int bi = 0;
                    #pragma unroll
                    for (int k = 0; k < K_P; ++k) {
                        const float ex = __fsub_rn(dx, __fmul_rn(kp[k * 3 + 0], das));
                        const float ey = __fsub_rn(dy, __fmul_rn(kp[k * 3 + 1], das));
                        const float ez = __fsub_rn(dz, __fmul_rn(kp[k * 3 + 2], das));
                        const float d2 = __fadd_rn(__fadd_rn(__fmul_rn(ex, ex), __fmul_rn(ey, ey)),
                                                   __fmul_rn(ez, ez));
                        if (d2 < best) { best = d2; bi = k; }
                    }
                    const float f = 1.f - sqrtf(best) / 0.9f;
                    fl = fmaxf(f, 0.f);
                    nn = bi;
                }
            }

            unsigned long long mask = __ballot(fl > 0.f);
            const int c0 = lane << 1;
            float2 acc = {0.f, 0.f};
            while (mask) {
                const int hb = __builtin_ctzll(mask);
                mask &= mask - 1;
                const int   ih = __shfl(idx, hb);
                const int   nh = __shfl(nn, hb);
                const float fh = __shfl(fl, hb);
                const float2 fv = *reinterpret_cast<const float2*>(s_feats + (size_t)ih * C_F + c0);
                const float2 wv = *reinterpret_cast<const float2*>(weights + nh * C_F + c0);
                const float  mv = modl[ql * MODC + nh * 16 + (lane >> 2)];
                const float  s  = fh * mv;
                acc.x = fmaf(fv.x * wv.x, s, acc.x);
                acc.y = fmaf(fv.y * wv.y, s, acc.y);
            }
            reinterpret_cast<float2*>(out + (size_t)mq * C_F)[lane] = acc;
        }
    }
}

// ---------------------------------------------------------------------------
extern "C" void kernel_launch(void* const* d_in, const int* in_sizes, int n_in,
                              void* d_out, int out_size, void* d_ws, size_t ws_size,
                              hipStream_t stream)
{
    const float* q_pts  = (const float*)d_in[0];
    const float* s_pts  = (const float*)d_in[1];
    const float* s_feat = (const float*)d_in[2];
    const int*   nbi    = (const int*)d_in[3];
    const float* da     = (const float*)d_in[4];
    const float* wts    = (const float*)d_in[5];
    const float* w1     = (const float*)d_in[6];
    const float* b1     = (const float*)d_in[7];
    const float* w2     = (const float*)d_in[8];
    const float* kp     = (const float*)d_in[9];
    float* out = (float*)d_out;

    const int M = in_sizes[4];   // da_scale has M elements

    // workspace: split/transposed weights, 184 KB total
    unsigned short* w1t_hi = (unsigned short*)d_ws;
    unsigned short* w1t_lo = w1t_hi + C_F * C_F;
    unsigned short* w2t_hi = w1t_lo + C_F * C_F;
    unsigned short* w2t_lo = w2t_hi + C_F * MODC;

    const int nsplit = (C_F * C_F + C_F * MODC + 255) / 256;
    split_w_kernel<<<dim3(nsplit), 256, 0, stream>>>(w1, w2, w1t_hi, w1t_lo, w2t_hi, w2t_lo);

    const int nb = (M + ROWS_B - 1) / ROWS_B;
    fused_kernel<<<dim3(nb), 512, 0, stream>>>(
        q_pts, s_pts, s_feat, nbi, da, wts, kp,
        w1t_hi, w1t_lo, w2t_hi, w2t_lo, b1, out, M);
}